// Round 1
// baseline (26.707 us; speedup 1.0000x reference)
//
#include <hip/hip_runtime.h>

// BilinearSparseRouting — collapsed form:
//   dots = softmax(const) = 1/32 exactly  =>
//   S[b] (4x4) = sum_j cp_mat[b,j] @ wc[j]
//   out[b,i]   = (1/32) * S[b] @ wn[i]
//
// current_pose: (256, 4096, 16) f32   -> 64 MiB (the only big read)
// w_current:    (1,1,4096,4,4) f32    -> 256 KiB (L2-resident)
// w_next:       (32,4,4) f32
// out:          (256,1,1,32,16) f32

#define BATCH 256
#define NIN   4096
#define NOUT  32

constexpr int CHUNKS  = 4;              // j-chunks per batch element
constexpr int THREADS = 256;
constexpr int JPER    = NIN / CHUNKS;   // 1024 j per block
constexpr int JPT     = JPER / THREADS; // 4 j per thread

__global__ __launch_bounds__(THREADS)
void caps_reduce(const float* __restrict__ cp,
                 const float* __restrict__ wc,
                 float* __restrict__ S /* BATCH*16 */) {
    const int b     = blockIdx.x / CHUNKS;
    const int chunk = blockIdx.x % CHUNKS;
    const int t     = threadIdx.x;

    float acc[16];
#pragma unroll
    for (int e = 0; e < 16; ++e) acc[e] = 0.f;

    const float* cpb = cp + ((size_t)b * NIN + (size_t)chunk * JPER) * 16;
    const float* wcc = wc + (size_t)chunk * JPER * 16;

#pragma unroll
    for (int it = 0; it < JPT; ++it) {
        const int j = it * THREADS + t;
        const float4* cp4 = (const float4*)(cpb + (size_t)j * 16);
        const float4* wc4 = (const float4*)(wcc + (size_t)j * 16);
        float a[16], w[16];
        *(float4*)&a[0]  = cp4[0];
        *(float4*)&a[4]  = cp4[1];
        *(float4*)&a[8]  = cp4[2];
        *(float4*)&a[12] = cp4[3];
        *(float4*)&w[0]  = wc4[0];
        *(float4*)&w[4]  = wc4[1];
        *(float4*)&w[8]  = wc4[2];
        *(float4*)&w[12] = wc4[3];
#pragma unroll
        for (int r = 0; r < 4; ++r)
#pragma unroll
            for (int c = 0; c < 4; ++c)
#pragma unroll
                for (int k = 0; k < 4; ++k)
                    acc[r * 4 + c] += a[r * 4 + k] * w[k * 4 + c];
    }

    // wave-level butterfly reduce (wave = 64 lanes on CDNA)
#pragma unroll
    for (int off = 32; off >= 1; off >>= 1) {
#pragma unroll
        for (int e = 0; e < 16; ++e)
            acc[e] += __shfl_xor(acc[e], off, 64);
    }

    __shared__ float red[THREADS / 64][16];
    const int wave = t >> 6;
    const int lane = t & 63;
    if (lane < 16) red[wave][lane] = acc[lane];
    __syncthreads();

    if (t < 16) {
        float v = red[0][t];
#pragma unroll
        for (int w2 = 1; w2 < THREADS / 64; ++w2) v += red[w2][t];
        atomicAdd(&S[b * 16 + t], v);
    }
}

__global__ __launch_bounds__(THREADS)
void caps_out(const float* __restrict__ S,
              const float* __restrict__ wn,
              float* __restrict__ out) {
    const int idx = blockIdx.x * THREADS + threadIdx.x; // 256*32*16 = 131072
    const int b   = idx >> 9;   // / 512
    const int rem = idx & 511;
    const int i   = rem >> 4;
    const int e   = rem & 15;
    const int r   = e >> 2;
    const int c   = e & 3;
    const float* Sb  = S + b * 16;
    const float* wni = wn + i * 16;
    float v = 0.f;
#pragma unroll
    for (int k = 0; k < 4; ++k) v += Sb[r * 4 + k] * wni[k * 4 + c];
    out[idx] = v * (1.0f / 32.0f);
}

extern "C" void kernel_launch(void* const* d_in, const int* in_sizes, int n_in,
                              void* d_out, int out_size, void* d_ws, size_t ws_size,
                              hipStream_t stream) {
    const float* cp = (const float*)d_in[0];   // (256,4096,16)
    const float* wc = (const float*)d_in[1];   // (1,1,4096,4,4)
    const float* wn = (const float*)d_in[2];   // (32,4,4)
    // d_in[3], d_in[4] = h_out, w_out (==1), unused
    float* out = (float*)d_out;
    float* S   = (float*)d_ws;                 // BATCH*16 floats = 16 KiB

    hipMemsetAsync(S, 0, BATCH * 16 * sizeof(float), stream);
    caps_reduce<<<BATCH * CHUNKS, THREADS, 0, stream>>>(cp, wc, S);
    caps_out<<<(BATCH * NOUT * 16) / THREADS, THREADS, 0, stream>>>(S, wn, out);
}

// Round 2
// 18.732 us; speedup vs baseline: 1.4257x; 1.4257x over previous
//
#include <hip/hip_runtime.h>

// BilinearSparseRouting — collapsed form (dots = softmax(const) = 1/32 exactly):
//   S[b] (4x4) = sum_j cp_mat[b,j] @ wc[j]
//   out[b,i]   = (1/32) * S[b] @ wn[i]
//
// Single fused kernel: 1 block per batch element (256 blocks = 256 CUs),
// 1024 threads/block, block-local reduction, epilogue in the same kernel.
// No workspace, no atomics, no memset.

#define BATCH 256
#define NIN   4096
#define NOUT  32

constexpr int THREADS = 1024;
constexpr int JPT     = NIN / THREADS;  // 4 j per thread

__global__ __launch_bounds__(THREADS)
void caps_fused(const float* __restrict__ cp,
                const float* __restrict__ wc,
                const float* __restrict__ wn,
                float* __restrict__ out) {
    const int b    = blockIdx.x;
    const int t    = threadIdx.x;
    const int lane = t & 63;
    const int wave = t >> 6;            // 16 waves

    float acc[16];
#pragma unroll
    for (int e = 0; e < 16; ++e) acc[e] = 0.f;

    const float* cpb = cp + (size_t)b * NIN * 16;

#pragma unroll
    for (int it = 0; it < JPT; ++it) {
        const int j = it * THREADS + t;
        const float4* cp4 = (const float4*)(cpb + (size_t)j * 16);
        const float4* wc4 = (const float4*)(wc + (size_t)j * 16);
        float a[16], w[16];
        *(float4*)&a[0]  = cp4[0];
        *(float4*)&a[4]  = cp4[1];
        *(float4*)&a[8]  = cp4[2];
        *(float4*)&a[12] = cp4[3];
        *(float4*)&w[0]  = wc4[0];
        *(float4*)&w[4]  = wc4[1];
        *(float4*)&w[8]  = wc4[2];
        *(float4*)&w[12] = wc4[3];
#pragma unroll
        for (int r = 0; r < 4; ++r)
#pragma unroll
            for (int c = 0; c < 4; ++c)
#pragma unroll
                for (int k = 0; k < 4; ++k)
                    acc[r * 4 + c] += a[r * 4 + k] * w[k * 4 + c];
    }

    // Halving butterfly: each step exchanges half the live accumulator.
    // 8+4+2+1 shuffles for masks 1,2,4,8; then 2 scalar shuffles for 16,32.
    // After the 4 halving steps lane l holds element
    //   e(l) = ((l&1)?8:0)|((l&2)?4:0)|((l&4)?2:0)|((l&8)?1:0)   (bit-reversal)
    {
        const bool hi1 = lane & 1;
#pragma unroll
        for (int e = 0; e < 8; ++e) {
            float a0 = acc[e], a1 = acc[e + 8];
            float send = hi1 ? a0 : a1;
            float keep = hi1 ? a1 : a0;
            acc[e] = keep + __shfl_xor(send, 1);
        }
        const bool hi2 = lane & 2;
#pragma unroll
        for (int e = 0; e < 4; ++e) {
            float a0 = acc[e], a1 = acc[e + 4];
            float send = hi2 ? a0 : a1;
            float keep = hi2 ? a1 : a0;
            acc[e] = keep + __shfl_xor(send, 2);
        }
        const bool hi4 = lane & 4;
#pragma unroll
        for (int e = 0; e < 2; ++e) {
            float a0 = acc[e], a1 = acc[e + 2];
            float send = hi4 ? a0 : a1;
            float keep = hi4 ? a1 : a0;
            acc[e] = keep + __shfl_xor(send, 4);
        }
        {
            const bool hi8 = lane & 8;
            float a0 = acc[0], a1 = acc[1];
            float send = hi8 ? a0 : a1;
            float keep = hi8 ? a1 : a0;
            acc[0] = keep + __shfl_xor(send, 8);
        }
        acc[0] += __shfl_xor(acc[0], 16);
        acc[0] += __shfl_xor(acc[0], 32);
    }

    __shared__ float red[16][16];   // [wave][element]
    __shared__ float S[16];
    if (lane < 16) {
        const int e = ((lane & 1) ? 8 : 0) | ((lane & 2) ? 4 : 0) |
                      ((lane & 4) ? 2 : 0) | ((lane & 8) ? 1 : 0);
        red[wave][e] = acc[0];
    }
    __syncthreads();

    if (t < 16) {
        float v = 0.f;
#pragma unroll
        for (int w2 = 0; w2 < 16; ++w2) v += red[w2][t];
        S[t] = v * (1.0f / 32.0f);
    }
    __syncthreads();

    // Epilogue: out[b,i,r,0..3] = S[r,:] @ wn[i][:,0..3], 128 threads x float4
    if (t < NOUT * 4) {
        const int i = t >> 2;
        const int r = t & 3;
        const float4* wn4 = (const float4*)(wn + i * 16);
        float4 w0 = wn4[0], w1 = wn4[1], w2 = wn4[2], w3 = wn4[3];
        float s0 = S[r * 4 + 0], s1 = S[r * 4 + 1], s2 = S[r * 4 + 2], s3 = S[r * 4 + 3];
        float4 o;
        o.x = s0 * w0.x + s1 * w1.x + s2 * w2.x + s3 * w3.x;
        o.y = s0 * w0.y + s1 * w1.y + s2 * w2.y + s3 * w3.y;
        o.z = s0 * w0.z + s1 * w1.z + s2 * w2.z + s3 * w3.z;
        o.w = s0 * w0.w + s1 * w1.w + s2 * w2.w + s3 * w3.w;
        ((float4*)(out + (size_t)b * NOUT * 16))[t] = o;
    }
}

extern "C" void kernel_launch(void* const* d_in, const int* in_sizes, int n_in,
                              void* d_out, int out_size, void* d_ws, size_t ws_size,
                              hipStream_t stream) {
    const float* cp = (const float*)d_in[0];   // (256,4096,16)
    const float* wc = (const float*)d_in[1];   // (1,1,4096,4,4)
    const float* wn = (const float*)d_in[2];   // (32,4,4)
    float* out = (float*)d_out;                // (256,1,1,32,16)

    caps_fused<<<BATCH, THREADS, 0, stream>>>(cp, wc, wn, out);
}